// Round 1
// baseline (442.198 us; speedup 1.0000x reference)
//
#include <hip/hip_runtime.h>

// MinimalThinkingRefiner: out = (mask[b,s]==2) ? x + alpha*(x*scale + shift) : x
// Shapes: x [4,4096,4096] f32, mask [4,4096] i32, scale/shift [4096] f32, alpha scalar f32.
// Memory-bound streaming kernel: float4 per lane, grid-stride.
// H = 4096 -> 1024 float4 per row; row index = i >> 10 (hardcoded to this shape).

#define H4 1024  // H / 4

__global__ __launch_bounds__(256) void MinimalThinkingRefiner_kernel(
    const float4* __restrict__ x,
    const int*    __restrict__ mask,
    const float*  __restrict__ scale,
    const float*  __restrict__ shift,
    const float*  __restrict__ alpha_p,
    float4*       __restrict__ out,
    int total4)
{
    const float alpha = *alpha_p;
    const int stride = gridDim.x * blockDim.x;
    for (int i = blockIdx.x * blockDim.x + threadIdx.x; i < total4; i += stride) {
        const int row  = i >> 10;        // i / H4
        const int col4 = i & (H4 - 1);   // i % H4
        const float4 xv = x[i];
        const int m = mask[row];         // row-uniform, L1/L2 hit
        const float4 sv = *(const float4*)(scale + (col4 << 2));
        const float4 tv = *(const float4*)(shift + (col4 << 2));
        // refined = x*s + t ; final = x + alpha*refined
        float4 o;
        o.x = fmaf(alpha, fmaf(xv.x, sv.x, tv.x), xv.x);
        o.y = fmaf(alpha, fmaf(xv.y, sv.y, tv.y), xv.y);
        o.z = fmaf(alpha, fmaf(xv.z, sv.z, tv.z), xv.z);
        o.w = fmaf(alpha, fmaf(xv.w, sv.w, tv.w), xv.w);
        if (m != 2) o = xv;              // non-thinking rows pass through
        out[i] = o;
    }
}

extern "C" void kernel_launch(void* const* d_in, const int* in_sizes, int n_in,
                              void* d_out, int out_size, void* d_ws, size_t ws_size,
                              hipStream_t stream) {
    const float4* x     = (const float4*)d_in[0];
    const int*    mask  = (const int*)  d_in[1];
    const float*  scale = (const float*)d_in[2];
    const float*  shift = (const float*)d_in[3];
    const float*  alpha = (const float*)d_in[4];
    float4*       out   = (float4*)d_out;

    const int total4 = out_size / 4;     // 16,777,216 float4
    const int block  = 256;
    const int grid   = 2048;             // 256 CUs x 8 blocks, grid-stride covers rest

    MinimalThinkingRefiner_kernel<<<grid, block, 0, stream>>>(
        x, mask, scale, shift, alpha, out, total4);
}